// Round 1
// baseline (77.901 us; speedup 1.0000x reference)
//
#include <hip/hip_runtime.h>
#include <math.h>

// Problem constants (from reference setup_inputs)
constexpr int S   = 4096;      // sequence length
constexpr int L   = S - 1;     // 4095 returns
constexpr int H2  = 128;       // hidden/2
constexpr int HID = 256;       // hidden
constexpr int NPOS = 16;       // window positions per thread (256*16 = 4096 >= L-w+1)
constexpr int WMAX = 20;
constexpr int RMAX = NPOS + WMAX - 1;  // 35 return values needed per thread
constexpr float LN_EPS = 1e-5f;

__device__ __forceinline__ float block_sum(float v, float* red, int tid) {
    red[tid] = v;
    __syncthreads();
    #pragma unroll
    for (int s = 128; s > 0; s >>= 1) {
        if (tid < s) red[tid] += red[tid + s];
        __syncthreads();
    }
    float r = red[0];
    __syncthreads();
    return r;
}

template<int W>
__device__ __forceinline__ float window_acc(const float (&rr)[RMAX], int t0) {
    // rolling unbiased std over window W, summed over this thread's valid positions
    float s1 = 0.f, s2 = 0.f;
    #pragma unroll
    for (int j = 0; j < W; ++j) { s1 += rr[j]; s2 = fmaf(rr[j], rr[j], s2); }
    float acc = 0.f;
    constexpr float invw   = 1.f / (float)W;
    constexpr float invwm1 = 1.f / (float)(W - 1);
    const int n = L - W + 1;   // number of window positions
    #pragma unroll
    for (int i = 0; i < NPOS; ++i) {
        if (t0 + i < n) {
            float var = (s2 - s1 * s1 * invw) * invwm1;
            acc += sqrtf(fmaxf(var, 0.f));
        }
        if (i < NPOS - 1) {  // slide (max index i+W = 14+20 = 34 < RMAX)
            float xin = rr[i + W], xout = rr[i];
            s1 += xin - xout;
            s2 += fmaf(xin, xin, -(xout * xout));
        }
    }
    return acc;
}

__global__ __launch_bounds__(256)
void vol_fused(const float* __restrict__ prices,
               const float* __restrict__ W1,  const float* __restrict__ b1,
               const float* __restrict__ g1,  const float* __restrict__ be1,
               const float* __restrict__ W2,  const float* __restrict__ b2,
               const float* __restrict__ g2,  const float* __restrict__ be2,
               const float* __restrict__ Wc1, const float* __restrict__ bc1,
               const float* __restrict__ Wc2, const float* __restrict__ bc2,
               float* __restrict__ out_combined, float* __restrict__ out_regime)
{
    __shared__ __align__(16) float lp[S + 40];  // log prices + zero pad
    __shared__ float red[256];
    __shared__ float comb[HID];                 // h (0..127) | h2f (128..255)
    __shared__ float c1s[64];
    __shared__ float lgt[4];
    __shared__ float vols[3];

    const int tid = threadIdx.x;
    const int b   = blockIdx.x;

    // ---- Phase 1: global -> LDS log prices (float4 vectorized) ----
    const float4* prow = reinterpret_cast<const float4*>(prices + (size_t)b * S);
    #pragma unroll
    for (int i = 0; i < S / (4 * 256); ++i) {
        int idx = tid + i * 256;          // float4 index 0..1023
        float4 v = prow[idx];
        lp[idx * 4 + 0] = logf(fmaxf(v.x, 1e-8f));
        lp[idx * 4 + 1] = logf(fmaxf(v.y, 1e-8f));
        lp[idx * 4 + 2] = logf(fmaxf(v.z, 1e-8f));
        lp[idx * 4 + 3] = logf(fmaxf(v.w, 1e-8f));
    }
    if (tid < 40) lp[S + tid] = 0.f;
    __syncthreads();

    // ---- Phase 2: per-thread register returns, sliding-window std sums ----
    const int t0 = tid * NPOS;            // first window position for this thread
    float lpv[RMAX + 1];                  // 36 consecutive log prices
    #pragma unroll
    for (int i = 0; i < (RMAX + 1) / 4; ++i) {   // 9 aligned float4 LDS reads
        float4 v = *reinterpret_cast<const float4*>(&lp[t0 + 4 * i]);
        lpv[4 * i + 0] = v.x; lpv[4 * i + 1] = v.y;
        lpv[4 * i + 2] = v.z; lpv[4 * i + 3] = v.w;
    }
    float rr[RMAX];
    #pragma unroll
    for (int i = 0; i < RMAX; ++i) rr[i] = lpv[i + 1] - lpv[i];

    float sum5  = window_acc<5>(rr, t0);
    float sum10 = window_acc<10>(rr, t0);
    float sum20 = window_acc<20>(rr, t0);

    float tot;
    tot = block_sum(sum5,  red, tid); if (tid == 0) vols[0] = tot / (float)(L - 5 + 1);
    tot = block_sum(sum10, red, tid); if (tid == 0) vols[1] = tot / (float)(L - 10 + 1);
    tot = block_sum(sum20, red, tid); if (tid == 0) vols[2] = tot / (float)(L - 20 + 1);
    __syncthreads();

    const float v0 = vols[0], v1 = vols[1], v2 = vols[2];

    // ---- Phase 3: layer 1 (only first 3 input dims nonzero) + LN ----
    float x = 0.f;
    if (tid < H2) {
        x = b1[tid];
        x = fmaf(v0, W1[0 * H2 + tid], x);
        x = fmaf(v1, W1[1 * H2 + tid], x);
        x = fmaf(v2, W1[2 * H2 + tid], x);
        x = fmaxf(x, 0.f);
    }
    float mu  = block_sum((tid < H2) ? x : 0.f, red, tid) * (1.f / H2);
    float d   = (tid < H2) ? (x - mu) : 0.f;
    float var = block_sum(d * d, red, tid) * (1.f / H2);
    if (tid < H2) {
        float h = d / sqrtf(var + LN_EPS) * g1[tid] + be1[tid];
        comb[tid] = h;
    }
    __syncthreads();

    // ---- Phase 4: layer 2 (128x128) + LN ----
    float x2 = 0.f;
    if (tid < H2) {
        x2 = b2[tid];
        #pragma unroll 4
        for (int k = 0; k < H2; ++k)
            x2 = fmaf(comb[k], W2[k * H2 + tid], x2);
        x2 = fmaxf(x2, 0.f);
    }
    mu  = block_sum((tid < H2) ? x2 : 0.f, red, tid) * (1.f / H2);
    d   = (tid < H2) ? (x2 - mu) : 0.f;
    var = block_sum(d * d, red, tid) * (1.f / H2);
    if (tid < H2) {
        float h2f = d / sqrtf(var + LN_EPS) * g2[tid] + be2[tid];
        comb[H2 + tid] = h2f;
    }
    __syncthreads();

    // ---- Phase 5: classifier 256->64 (relu) -> 4 -> softmax ----
    if (tid < 64) {
        float c = bc1[tid];
        #pragma unroll 4
        for (int k = 0; k < HID; ++k)
            c = fmaf(comb[k], Wc1[k * 64 + tid], c);
        c1s[tid] = fmaxf(c, 0.f);
    }
    __syncthreads();
    if (tid < 4) {
        float lg = bc2[tid];
        #pragma unroll
        for (int j = 0; j < 64; ++j)
            lg = fmaf(c1s[j], Wc2[j * 4 + tid], lg);
        lgt[tid] = lg;
    }
    __syncthreads();
    if (tid < 4) {
        float m  = fmaxf(fmaxf(lgt[0], lgt[1]), fmaxf(lgt[2], lgt[3]));
        float e0 = expf(lgt[0] - m), e1 = expf(lgt[1] - m);
        float e2 = expf(lgt[2] - m), e3 = expf(lgt[3] - m);
        float mine = (tid == 0) ? e0 : (tid == 1) ? e1 : (tid == 2) ? e2 : e3;
        out_regime[(size_t)b * 4 + tid] = mine / (e0 + e1 + e2 + e3);
    }

    // ---- Phase 6: write combined ----
    out_combined[(size_t)b * HID + tid] = comb[tid];
}

extern "C" void kernel_launch(void* const* d_in, const int* in_sizes, int n_in,
                              void* d_out, int out_size, void* d_ws, size_t ws_size,
                              hipStream_t stream) {
    const float* prices = (const float*)d_in[0];
    const float* W1  = (const float*)d_in[1];
    const float* b1  = (const float*)d_in[2];
    const float* g1  = (const float*)d_in[3];
    const float* be1 = (const float*)d_in[4];
    const float* W2  = (const float*)d_in[5];
    const float* b2  = (const float*)d_in[6];
    const float* g2  = (const float*)d_in[7];
    const float* be2 = (const float*)d_in[8];
    const float* Wc1 = (const float*)d_in[9];
    const float* bc1 = (const float*)d_in[10];
    const float* Wc2 = (const float*)d_in[11];
    const float* bc2 = (const float*)d_in[12];

    const int B = in_sizes[0] / S;                 // 4096
    float* out_combined = (float*)d_out;
    float* out_regime   = (float*)d_out + (size_t)B * HID;

    vol_fused<<<B, 256, 0, stream>>>(prices, W1, b1, g1, be1, W2, b2, g2, be2,
                                     Wc1, bc1, Wc2, bc2, out_combined, out_regime);
}

// Round 2
// 50.406 us; speedup vs baseline: 1.5455x; 1.5455x over previous
//
#include <hip/hip_runtime.h>
#include <math.h>

constexpr int S   = 4096;
constexpr int L   = S - 1;     // 4095 returns
constexpr int H2  = 128;
constexpr int HID = 256;
constexpr int NPOS = 16;       // window positions per thread
constexpr int WMAX = 20;
constexpr int RMAX = NPOS + WMAX - 1;  // 35
constexpr float LN_EPS = 1e-5f;

__device__ __forceinline__ float fast_sqrt(float x) { return __builtin_amdgcn_sqrtf(x); }
__device__ __forceinline__ float fast_rsqrt(float x) { return __builtin_amdgcn_rsqf(x); }

// sum (a,b) over all 256 threads; 2 barriers. red must hold >= 8 floats.
__device__ __forceinline__ float2 block_sum2(float a, float b, int tid, float* red) {
    #pragma unroll
    for (int off = 32; off; off >>= 1) {
        a += __shfl_down(a, off);
        b += __shfl_down(b, off);
    }
    if ((tid & 63) == 0) { red[(tid >> 6) * 2] = a; red[(tid >> 6) * 2 + 1] = b; }
    __syncthreads();
    float2 r = make_float2(red[0] + red[2] + red[4] + red[6],
                           red[1] + red[3] + red[5] + red[7]);
    __syncthreads();
    return r;
}

template<int W>
__device__ __forceinline__ float window_acc(const float (&rr)[RMAX], int t0) {
    float s1 = 0.f, s2 = 0.f;
    #pragma unroll
    for (int j = 0; j < W; ++j) { s1 += rr[j]; s2 = fmaf(rr[j], rr[j], s2); }
    float acc = 0.f;
    constexpr float invw   = 1.f / (float)W;
    constexpr float invwm1 = 1.f / (float)(W - 1);
    const int n = L - W + 1;
    #pragma unroll
    for (int i = 0; i < NPOS; ++i) {
        if (t0 + i < n) {
            float var = (s2 - s1 * s1 * invw) * invwm1;
            acc += fast_sqrt(fmaxf(var, 0.f));
        }
        if (i < NPOS - 1) {
            float xin = rr[i + W], xout = rr[i];
            s1 += xin - xout;
            s2 += fmaf(xin, xin, -(xout * xout));
        }
    }
    return acc;
}

__global__ __launch_bounds__(256)
void vol_fused(const float* __restrict__ prices,
               const float* __restrict__ W1,  const float* __restrict__ b1,
               const float* __restrict__ g1,  const float* __restrict__ be1,
               const float* __restrict__ W2,  const float* __restrict__ b2,
               const float* __restrict__ g2,  const float* __restrict__ be2,
               const float* __restrict__ Wc1, const float* __restrict__ bc1,
               const float* __restrict__ Wc2, const float* __restrict__ bc2,
               float* __restrict__ out_combined, float* __restrict__ out_regime)
{
    __shared__ __align__(16) float lp[S + 40];
    __shared__ float red[256];
    __shared__ float comb[HID];
    __shared__ float c1s[64];
    __shared__ float vols[4];

    const int tid = threadIdx.x;
    const int b   = blockIdx.x;

    // ---- Phase 1: global -> LDS log prices (fast log) ----
    const float4* prow = reinterpret_cast<const float4*>(prices + (size_t)b * S);
    #pragma unroll
    for (int i = 0; i < S / (4 * 256); ++i) {
        int idx = tid + i * 256;
        float4 v = prow[idx];
        lp[idx * 4 + 0] = __logf(fmaxf(v.x, 1e-8f));
        lp[idx * 4 + 1] = __logf(fmaxf(v.y, 1e-8f));
        lp[idx * 4 + 2] = __logf(fmaxf(v.z, 1e-8f));
        lp[idx * 4 + 3] = __logf(fmaxf(v.w, 1e-8f));
    }
    if (tid < 40) lp[S + tid] = 0.f;
    __syncthreads();

    // ---- Phase 2: per-thread sliding-window std sums ----
    const int t0 = tid * NPOS;
    float lpv[RMAX + 1];
    #pragma unroll
    for (int i = 0; i < (RMAX + 1) / 4; ++i) {
        float4 v = *reinterpret_cast<const float4*>(&lp[t0 + 4 * i]);
        lpv[4 * i + 0] = v.x; lpv[4 * i + 1] = v.y;
        lpv[4 * i + 2] = v.z; lpv[4 * i + 3] = v.w;
    }
    float rr[RMAX];
    #pragma unroll
    for (int i = 0; i < RMAX; ++i) rr[i] = lpv[i + 1] - lpv[i];

    float sum5  = window_acc<5>(rr, t0);
    float sum10 = window_acc<10>(rr, t0);
    float sum20 = window_acc<20>(rr, t0);

    // 3-value cross-block reduction: one shuffle pass + one LDS combine
    #pragma unroll
    for (int off = 32; off; off >>= 1) {
        sum5  += __shfl_down(sum5,  off);
        sum10 += __shfl_down(sum10, off);
        sum20 += __shfl_down(sum20, off);
    }
    if ((tid & 63) == 0) {
        int w = tid >> 6;
        red[w * 3 + 0] = sum5; red[w * 3 + 1] = sum10; red[w * 3 + 2] = sum20;
    }
    __syncthreads();
    if (tid < 3) {
        constexpr float sc[3] = { 1.f / (L - 5 + 1), 1.f / (L - 10 + 1), 1.f / (L - 20 + 1) };
        vols[tid] = (red[tid] + red[3 + tid] + red[6 + tid] + red[9 + tid]) * sc[tid];
    }
    __syncthreads();

    const float v0 = vols[0], v1 = vols[1], v2 = vols[2];

    // ---- Phase 3: layer 1 (3 nonzero inputs) + LN (fused mean/meansq) ----
    float x = 0.f;
    if (tid < H2) {
        x = b1[tid];
        x = fmaf(v0, W1[0 * H2 + tid], x);
        x = fmaf(v1, W1[1 * H2 + tid], x);
        x = fmaf(v2, W1[2 * H2 + tid], x);
        x = fmaxf(x, 0.f);
    }
    float2 s = block_sum2((tid < H2) ? x : 0.f, (tid < H2) ? x * x : 0.f, tid, red);
    {
        float mu  = s.x * (1.f / H2);
        float var = s.y * (1.f / H2) - mu * mu;
        if (tid < H2)
            comb[tid] = (x - mu) * fast_rsqrt(fmaxf(var, 0.f) + LN_EPS) * g1[tid] + be1[tid];
    }
    __syncthreads();

    // ---- Phase 4: layer 2 (128x128), all 256 threads: 2-way k-split ----
    {
        const int j = tid & 127, h = tid >> 7;
        const float* w2p = W2 + j;
        const int kb = h << 6;
        float a0 = 0.f, a1 = 0.f, a2 = 0.f, a3 = 0.f;
        #pragma unroll
        for (int k = 0; k < 64; k += 4) {
            int kk = kb + k;
            a0 = fmaf(comb[kk + 0], w2p[(size_t)(kk + 0) * H2], a0);
            a1 = fmaf(comb[kk + 1], w2p[(size_t)(kk + 1) * H2], a1);
            a2 = fmaf(comb[kk + 2], w2p[(size_t)(kk + 2) * H2], a2);
            a3 = fmaf(comb[kk + 3], w2p[(size_t)(kk + 3) * H2], a3);
        }
        red[tid] = (a0 + a1) + (a2 + a3);
    }
    __syncthreads();
    float x2 = 0.f;
    if (tid < H2) x2 = fmaxf(red[tid] + red[tid + 128] + b2[tid], 0.f);
    __syncthreads();  // red reused inside block_sum2
    s = block_sum2((tid < H2) ? x2 : 0.f, (tid < H2) ? x2 * x2 : 0.f, tid, red);
    {
        float mu  = s.x * (1.f / H2);
        float var = s.y * (1.f / H2) - mu * mu;
        if (tid < H2)
            comb[H2 + tid] = (x2 - mu) * fast_rsqrt(fmaxf(var, 0.f) + LN_EPS) * g2[tid] + be2[tid];
    }
    __syncthreads();

    // write combined early (all 256 values ready)
    out_combined[(size_t)b * HID + tid] = comb[tid];

    // ---- Phase 5: classifier 256->64, all 256 threads: 4-way k-split ----
    {
        const int j = tid & 63, q = tid >> 6;
        const float* wcp = Wc1 + j;
        const int kb = q << 6;
        float a0 = 0.f, a1 = 0.f, a2 = 0.f, a3 = 0.f;
        #pragma unroll
        for (int k = 0; k < 64; k += 4) {
            int kk = kb + k;
            a0 = fmaf(comb[kk + 0], wcp[(size_t)(kk + 0) * 64], a0);
            a1 = fmaf(comb[kk + 1], wcp[(size_t)(kk + 1) * 64], a1);
            a2 = fmaf(comb[kk + 2], wcp[(size_t)(kk + 2) * 64], a2);
            a3 = fmaf(comb[kk + 3], wcp[(size_t)(kk + 3) * 64], a3);
        }
        red[tid] = (a0 + a1) + (a2 + a3);
    }
    __syncthreads();
    if (tid < 64)
        c1s[tid] = fmaxf(red[tid] + red[tid + 64] + red[tid + 128] + red[tid + 192] + bc1[tid], 0.f);
    __syncthreads();

    // ---- Phase 6: 64->4 logits + softmax (4 threads, 4 accumulators) ----
    if (tid < 4) {
        const float* wc2 = Wc2 + tid;
        float a0 = 0.f, a1 = 0.f, a2 = 0.f, a3 = 0.f;
        #pragma unroll
        for (int k = 0; k < 64; k += 4) {
            a0 = fmaf(c1s[k + 0], wc2[(k + 0) * 4], a0);
            a1 = fmaf(c1s[k + 1], wc2[(k + 1) * 4], a1);
            a2 = fmaf(c1s[k + 2], wc2[(k + 2) * 4], a2);
            a3 = fmaf(c1s[k + 3], wc2[(k + 3) * 4], a3);
        }
        red[tid] = (a0 + a1) + (a2 + a3) + bc2[tid];
    }
    __syncthreads();
    if (tid < 4) {
        float l0 = red[0], l1 = red[1], l2 = red[2], l3 = red[3];
        float m  = fmaxf(fmaxf(l0, l1), fmaxf(l2, l3));
        float e0 = __expf(l0 - m), e1 = __expf(l1 - m);
        float e2 = __expf(l2 - m), e3 = __expf(l3 - m);
        float mine = (tid == 0) ? e0 : (tid == 1) ? e1 : (tid == 2) ? e2 : e3;
        out_regime[(size_t)b * 4 + tid] = mine / (e0 + e1 + e2 + e3);
    }
}

extern "C" void kernel_launch(void* const* d_in, const int* in_sizes, int n_in,
                              void* d_out, int out_size, void* d_ws, size_t ws_size,
                              hipStream_t stream) {
    const float* prices = (const float*)d_in[0];
    const float* W1  = (const float*)d_in[1];
    const float* b1  = (const float*)d_in[2];
    const float* g1  = (const float*)d_in[3];
    const float* be1 = (const float*)d_in[4];
    const float* W2  = (const float*)d_in[5];
    const float* b2  = (const float*)d_in[6];
    const float* g2  = (const float*)d_in[7];
    const float* be2 = (const float*)d_in[8];
    const float* Wc1 = (const float*)d_in[9];
    const float* bc1 = (const float*)d_in[10];
    const float* Wc2 = (const float*)d_in[11];
    const float* bc2 = (const float*)d_in[12];

    const int B = in_sizes[0] / S;
    float* out_combined = (float*)d_out;
    float* out_regime   = (float*)d_out + (size_t)B * HID;

    vol_fused<<<B, 256, 0, stream>>>(prices, W1, b1, g1, be1, W2, b2, g2, be2,
                                     Wc1, bc1, Wc2, bc2, out_combined, out_regime);
}

// Round 3
// 43.857 us; speedup vs baseline: 1.7763x; 1.1493x over previous
//
#include <hip/hip_runtime.h>
#include <math.h>

constexpr int S   = 4096;
constexpr int L   = S - 1;     // 4095 returns
constexpr int H2  = 128;
constexpr int HID = 256;
constexpr int NPOS = 16;       // window positions per thread
constexpr int WMAX = 20;
constexpr int RMAX = NPOS + WMAX - 1;  // 35
constexpr float LN_EPS = 1e-5f;

__device__ __forceinline__ float fast_sqrt(float x) { return __builtin_amdgcn_sqrtf(x); }
__device__ __forceinline__ float fast_rsqrt(float x) { return __builtin_amdgcn_rsqf(x); }

// sum (a,b) over all 256 threads; 2 barriers. red8 holds 8 floats.
__device__ __forceinline__ float2 block_sum2(float a, float b, int tid, float* red8) {
    #pragma unroll
    for (int off = 32; off; off >>= 1) {
        a += __shfl_down(a, off);
        b += __shfl_down(b, off);
    }
    if ((tid & 63) == 0) { red8[(tid >> 6) * 2] = a; red8[(tid >> 6) * 2 + 1] = b; }
    __syncthreads();
    float2 r = make_float2(red8[0] + red8[2] + red8[4] + red8[6],
                           red8[1] + red8[3] + red8[5] + red8[7]);
    __syncthreads();
    return r;
}

template<int W>
__device__ __forceinline__ float window_acc(const float (&rr)[RMAX], int t0) {
    float s1 = 0.f, s2 = 0.f;
    #pragma unroll
    for (int j = 0; j < W; ++j) { s1 += rr[j]; s2 = fmaf(rr[j], rr[j], s2); }
    float acc = 0.f;
    constexpr float invw   = 1.f / (float)W;
    constexpr float invwm1 = 1.f / (float)(W - 1);
    const int n = L - W + 1;
    #pragma unroll
    for (int i = 0; i < NPOS; ++i) {
        if (t0 + i < n) {
            float var = (s2 - s1 * s1 * invw) * invwm1;
            acc += fast_sqrt(fmaxf(var, 0.f));
        }
        if (i < NPOS - 1) {
            float xin = rr[i + W], xout = rr[i];
            s1 += xin - xout;
            s2 += fmaf(xin, xin, -(xout * xout));
        }
    }
    return acc;
}

__global__ __launch_bounds__(256)
void vol_fused(const float* __restrict__ prices,
               const float* __restrict__ W1,  const float* __restrict__ b1,
               const float* __restrict__ g1,  const float* __restrict__ be1,
               const float* __restrict__ W2,  const float* __restrict__ b2,
               const float* __restrict__ g2,  const float* __restrict__ be2,
               const float* __restrict__ Wc1, const float* __restrict__ bc1,
               const float* __restrict__ Wc2, const float* __restrict__ bc2,
               float* __restrict__ out_combined, float* __restrict__ out_regime)
{
    __shared__ __align__(16) float lp[S + 40];
    __shared__ __align__(16) float part[1024];   // [segs][quads] float4 partials (4 KB)
    __shared__ float red8[8];
    __shared__ float redv[16];
    __shared__ float comb[HID];
    __shared__ float vols[4];

    const int tid = threadIdx.x;
    const int b   = blockIdx.x;

    // ---- Phase 1: global -> LDS log prices (fast log) ----
    const float4* prow = reinterpret_cast<const float4*>(prices + (size_t)b * S);
    #pragma unroll
    for (int i = 0; i < S / (4 * 256); ++i) {
        int idx = tid + i * 256;
        float4 v = prow[idx];
        lp[idx * 4 + 0] = __logf(fmaxf(v.x, 1e-8f));
        lp[idx * 4 + 1] = __logf(fmaxf(v.y, 1e-8f));
        lp[idx * 4 + 2] = __logf(fmaxf(v.z, 1e-8f));
        lp[idx * 4 + 3] = __logf(fmaxf(v.w, 1e-8f));
    }
    if (tid < 40) lp[S + tid] = 0.f;
    __syncthreads();

    // ---- Phase 2: per-thread sliding-window std sums ----
    const int t0 = tid * NPOS;
    float lpv[RMAX + 1];
    #pragma unroll
    for (int i = 0; i < (RMAX + 1) / 4; ++i) {
        float4 v = *reinterpret_cast<const float4*>(&lp[t0 + 4 * i]);
        lpv[4 * i + 0] = v.x; lpv[4 * i + 1] = v.y;
        lpv[4 * i + 2] = v.z; lpv[4 * i + 3] = v.w;
    }
    float rr[RMAX];
    #pragma unroll
    for (int i = 0; i < RMAX; ++i) rr[i] = lpv[i + 1] - lpv[i];

    float sum5  = window_acc<5>(rr, t0);
    float sum10 = window_acc<10>(rr, t0);
    float sum20 = window_acc<20>(rr, t0);

    #pragma unroll
    for (int off = 32; off; off >>= 1) {
        sum5  += __shfl_down(sum5,  off);
        sum10 += __shfl_down(sum10, off);
        sum20 += __shfl_down(sum20, off);
    }
    if ((tid & 63) == 0) {
        int w = tid >> 6;
        redv[w * 3 + 0] = sum5; redv[w * 3 + 1] = sum10; redv[w * 3 + 2] = sum20;
    }
    __syncthreads();
    if (tid < 3) {
        constexpr float sc[3] = { 1.f / (L - 5 + 1), 1.f / (L - 10 + 1), 1.f / (L - 20 + 1) };
        vols[tid] = (redv[tid] + redv[3 + tid] + redv[6 + tid] + redv[9 + tid]) * sc[tid];
    }
    __syncthreads();

    const float v0 = vols[0], v1 = vols[1], v2 = vols[2];

    // ---- Phase 3: layer 1 (3 nonzero inputs) + LN ----
    float x = 0.f;
    if (tid < H2) {
        x = b1[tid];
        x = fmaf(v0, W1[0 * H2 + tid], x);
        x = fmaf(v1, W1[1 * H2 + tid], x);
        x = fmaf(v2, W1[2 * H2 + tid], x);
        x = fmaxf(x, 0.f);
    }
    float2 s = block_sum2((tid < H2) ? x : 0.f, (tid < H2) ? x * x : 0.f, tid, red8);
    {
        float mu  = s.x * (1.f / H2);
        float var = s.y * (1.f / H2) - mu * mu;
        if (tid < H2)
            comb[tid] = (x - mu) * fast_rsqrt(fmaxf(var, 0.f) + LN_EPS) * g1[tid] + be1[tid];
    }
    __syncthreads();

    // ---- Phase 4: layer 2 (128x128), quad-col x k-segment GEMV ----
    {
        const int q = tid & 31, seg = tid >> 3 >> 2;   // q: col-quad 0..31, seg: 0..7
        const float* w2base = W2 + (size_t)(seg * 16) * H2 + q * 4;
        float ax = 0.f, ay = 0.f, az = 0.f, aw = 0.f;
        #pragma unroll
        for (int k = 0; k < 16; ++k) {
            float a = comb[seg * 16 + k];
            float4 w = *reinterpret_cast<const float4*>(w2base + (size_t)k * H2);
            ax = fmaf(a, w.x, ax); ay = fmaf(a, w.y, ay);
            az = fmaf(a, w.z, az); aw = fmaf(a, w.w, aw);
        }
        float4* p4 = reinterpret_cast<float4*>(part);
        p4[tid] = make_float4(ax, ay, az, aw);     // part[(seg*32+q)*4 + c]
    }
    __syncthreads();
    float x2 = 0.f;
    if (tid < H2) {
        float ssum = 0.f;
        #pragma unroll
        for (int sg = 0; sg < 8; ++sg) ssum += part[sg * 128 + tid];
        x2 = fmaxf(ssum + b2[tid], 0.f);
    }
    s = block_sum2((tid < H2) ? x2 : 0.f, (tid < H2) ? x2 * x2 : 0.f, tid, red8);
    {
        float mu  = s.x * (1.f / H2);
        float var = s.y * (1.f / H2) - mu * mu;
        if (tid < H2)
            comb[H2 + tid] = (x2 - mu) * fast_rsqrt(fmaxf(var, 0.f) + LN_EPS) * g2[tid] + be2[tid];
    }
    __syncthreads();

    // write combined (all 256 values ready; also fences comb for phase 5)
    out_combined[(size_t)b * HID + tid] = comb[tid];

    // ---- Phase 5: classifier 256->64, quad-col x k-segment GEMV ----
    {
        const int q = tid & 15, seg = tid >> 4;        // q: 0..15, seg: 0..15
        const float* wcbase = Wc1 + (size_t)(seg * 16) * 64 + q * 4;
        float ax = 0.f, ay = 0.f, az = 0.f, aw = 0.f;
        #pragma unroll
        for (int k = 0; k < 16; ++k) {
            float a = comb[seg * 16 + k];
            float4 w = *reinterpret_cast<const float4*>(wcbase + (size_t)k * 64);
            ax = fmaf(a, w.x, ax); ay = fmaf(a, w.y, ay);
            az = fmaf(a, w.z, az); aw = fmaf(a, w.w, aw);
        }
        float4* p4 = reinterpret_cast<float4*>(part);
        p4[tid] = make_float4(ax, ay, az, aw);     // part[(seg*16+q)*4 + c]
    }
    __syncthreads();

    // ---- Phase 6: 64->4 logits + softmax, single wave ----
    if (tid < 64) {
        float ssum = 0.f;
        #pragma unroll
        for (int sg = 0; sg < 16; ++sg) ssum += part[sg * 64 + tid];
        float c1 = fmaxf(ssum + bc1[tid], 0.f);

        float4 wrow = reinterpret_cast<const float4*>(Wc2)[tid];   // Wc2[j][0..3]
        float lx = c1 * wrow.x, ly = c1 * wrow.y, lz = c1 * wrow.z, lw = c1 * wrow.w;
        #pragma unroll
        for (int off = 32; off; off >>= 1) {
            lx += __shfl_down(lx, off);
            ly += __shfl_down(ly, off);
            lz += __shfl_down(lz, off);
            lw += __shfl_down(lw, off);
        }
        if (tid == 0) {
            float4 bb = *reinterpret_cast<const float4*>(bc2);
            float l0 = lx + bb.x, l1 = ly + bb.y, l2 = lz + bb.z, l3 = lw + bb.w;
            float m  = fmaxf(fmaxf(l0, l1), fmaxf(l2, l3));
            float e0 = __expf(l0 - m), e1 = __expf(l1 - m);
            float e2 = __expf(l2 - m), e3 = __expf(l3 - m);
            float inv = 1.f / (e0 + e1 + e2 + e3);
            reinterpret_cast<float4*>(out_regime)[b] =
                make_float4(e0 * inv, e1 * inv, e2 * inv, e3 * inv);
        }
    }
}

extern "C" void kernel_launch(void* const* d_in, const int* in_sizes, int n_in,
                              void* d_out, int out_size, void* d_ws, size_t ws_size,
                              hipStream_t stream) {
    const float* prices = (const float*)d_in[0];
    const float* W1  = (const float*)d_in[1];
    const float* b1  = (const float*)d_in[2];
    const float* g1  = (const float*)d_in[3];
    const float* be1 = (const float*)d_in[4];
    const float* W2  = (const float*)d_in[5];
    const float* b2  = (const float*)d_in[6];
    const float* g2  = (const float*)d_in[7];
    const float* be2 = (const float*)d_in[8];
    const float* Wc1 = (const float*)d_in[9];
    const float* bc1 = (const float*)d_in[10];
    const float* Wc2 = (const float*)d_in[11];
    const float* bc2 = (const float*)d_in[12];

    const int B = in_sizes[0] / S;
    float* out_combined = (float*)d_out;
    float* out_regime   = (float*)d_out + (size_t)B * HID;

    vol_fused<<<B, 256, 0, stream>>>(prices, W1, b1, g1, be1, W2, b2, g2, be2,
                                     Wc1, bc1, Wc2, bc2, out_combined, out_regime);
}

// Round 4
// 43.651 us; speedup vs baseline: 1.7846x; 1.0047x over previous
//
#include <hip/hip_runtime.h>
#include <math.h>

constexpr int S   = 4096;
constexpr int L   = S - 1;     // 4095 returns
constexpr int H2  = 128;
constexpr int HID = 256;
constexpr int NPOS = 16;       // window positions per thread
constexpr int WMAX = 20;
constexpr int RMAX = NPOS + WMAX - 1;  // 35
constexpr float LN_EPS = 1e-5f;

constexpr int LP4 = 1040;      // float4 slots: 1024 data + 16 pad

__device__ __forceinline__ float fast_sqrt(float x)  { return __builtin_amdgcn_sqrtf(x); }
__device__ __forceinline__ float fast_rsqrt(float x) { return __builtin_amdgcn_rsqf(x); }

// XOR-swizzle on float4-slot index: spreads the stride-4-slot phase-2 reads
// across all 4 bank groups (was: all 64 lanes on one 4-bank group = ~32-way).
__device__ __forceinline__ int swz(int slot) { return slot ^ ((slot >> 2) & 3); }

// sum (a,b) over all 256 threads; 2 barriers. red8 holds 8 floats.
__device__ __forceinline__ float2 block_sum2(float a, float b, int tid, float* red8) {
    #pragma unroll
    for (int off = 32; off; off >>= 1) {
        a += __shfl_down(a, off);
        b += __shfl_down(b, off);
    }
    if ((tid & 63) == 0) { red8[(tid >> 6) * 2] = a; red8[(tid >> 6) * 2 + 1] = b; }
    __syncthreads();
    float2 r = make_float2(red8[0] + red8[2] + red8[4] + red8[6],
                           red8[1] + red8[3] + red8[5] + red8[7]);
    __syncthreads();
    return r;
}

template<int W>
__device__ __forceinline__ float window_acc(const float (&rr)[RMAX], int t0,
                                            float s1, float s2) {
    // std = sqrt(s2*c1 - s1^2*c2), c1 = 1/(W-1), c2 = 1/(W*(W-1))
    constexpr float c1 = 1.f / (float)(W - 1);
    constexpr float c2 = 1.f / ((float)W * (float)(W - 1));
    const int n = L - W + 1;
    float acc = 0.f;
    #pragma unroll
    for (int i = 0; i < NPOS; ++i) {
        float t  = fmaf(-(s1 * c2), s1, s2 * c1);
        float sd = fast_sqrt(fmaxf(t, 0.f));
        if (t0 + i < n) acc += sd;
        if (i < NPOS - 1) {
            float xin = rr[i + W], xout = rr[i];
            s1 += xin; s1 -= xout;
            s2 = fmaf(xin, xin, s2);
            s2 = fmaf(-xout, xout, s2);
        }
    }
    return acc;
}

__global__ __launch_bounds__(256)
void vol_fused(const float* __restrict__ prices,
               const float* __restrict__ W1,  const float* __restrict__ b1,
               const float* __restrict__ g1,  const float* __restrict__ be1,
               const float* __restrict__ W2,  const float* __restrict__ b2,
               const float* __restrict__ g2,  const float* __restrict__ be2,
               const float* __restrict__ Wc1, const float* __restrict__ bc1,
               const float* __restrict__ Wc2, const float* __restrict__ bc2,
               float* __restrict__ out_combined, float* __restrict__ out_regime)
{
    __shared__ __align__(16) float4 lp4[LP4];   // 16.6 KB; reused by MLP phases
    __shared__ float redv[16];
    __shared__ float vols[4];

    // lp region is dead after phase 2 (all reads precede the first barrier);
    // alias the MLP scratch onto it to cut LDS 22K -> 16.7K (9 blocks/CU).
    float* fbuf = reinterpret_cast<float*>(lp4);
    float* comb = fbuf;          // 256 floats
    float* part = fbuf + 256;    // 1024 floats (16B-aligned: 1024B offset)
    float* red8 = fbuf + 1280;   // 8 floats

    const int tid = threadIdx.x;
    const int b   = blockIdx.x;

    // ---- Phase 1: global -> LDS log prices (fast log), swizzled store ----
    const float4* prow = reinterpret_cast<const float4*>(prices + (size_t)b * S);
    #pragma unroll
    for (int i = 0; i < 4; ++i) {
        int slot = tid + i * 256;
        float4 v = prow[slot];
        float4 w;
        w.x = __logf(fmaxf(v.x, 1e-8f));
        w.y = __logf(fmaxf(v.y, 1e-8f));
        w.z = __logf(fmaxf(v.z, 1e-8f));
        w.w = __logf(fmaxf(v.w, 1e-8f));
        lp4[swz(slot)] = w;
    }
    if (tid < 16) lp4[swz(1024 + tid)] = make_float4(0.f, 0.f, 0.f, 0.f);
    __syncthreads();

    // ---- Phase 2: per-thread sliding-window std sums (swizzled reads) ----
    const int t0 = tid * NPOS;
    const int st = tid * 4;               // first float4 slot of this thread
    float lpv[36];
    #pragma unroll
    for (int j = 0; j < 9; ++j) {
        float4 v = lp4[swz(st + j)];
        lpv[4 * j + 0] = v.x; lpv[4 * j + 1] = v.y;
        lpv[4 * j + 2] = v.z; lpv[4 * j + 3] = v.w;
    }
    float rr[RMAX];
    #pragma unroll
    for (int i = 0; i < RMAX; ++i) rr[i] = lpv[i + 1] - lpv[i];

    // shared window-sum inits: s(5) -> s(10) -> s(20)
    float s1a = 0.f, s2a = 0.f;
    #pragma unroll
    for (int j = 0; j < 5; ++j) { s1a += rr[j]; s2a = fmaf(rr[j], rr[j], s2a); }
    float s1b = s1a, s2b = s2a;
    #pragma unroll
    for (int j = 5; j < 10; ++j) { s1b += rr[j]; s2b = fmaf(rr[j], rr[j], s2b); }
    float s1c = s1b, s2c = s2b;
    #pragma unroll
    for (int j = 10; j < 20; ++j) { s1c += rr[j]; s2c = fmaf(rr[j], rr[j], s2c); }

    float sum5  = window_acc<5>(rr, t0, s1a, s2a);
    float sum10 = window_acc<10>(rr, t0, s1b, s2b);
    float sum20 = window_acc<20>(rr, t0, s1c, s2c);

    #pragma unroll
    for (int off = 32; off; off >>= 1) {
        sum5  += __shfl_down(sum5,  off);
        sum10 += __shfl_down(sum10, off);
        sum20 += __shfl_down(sum20, off);
    }
    if ((tid & 63) == 0) {
        int w = tid >> 6;
        redv[w * 3 + 0] = sum5; redv[w * 3 + 1] = sum10; redv[w * 3 + 2] = sum20;
    }
    __syncthreads();                       // after this, lp region is dead
    if (tid < 3) {
        constexpr float sc[3] = { 1.f / (L - 5 + 1), 1.f / (L - 10 + 1), 1.f / (L - 20 + 1) };
        vols[tid] = (redv[tid] + redv[3 + tid] + redv[6 + tid] + redv[9 + tid]) * sc[tid];
    }
    __syncthreads();

    const float v0 = vols[0], v1 = vols[1], v2 = vols[2];

    // ---- Phase 3: layer 1 (3 nonzero inputs) + LN ----
    float x = 0.f;
    if (tid < H2) {
        x = b1[tid];
        x = fmaf(v0, W1[0 * H2 + tid], x);
        x = fmaf(v1, W1[1 * H2 + tid], x);
        x = fmaf(v2, W1[2 * H2 + tid], x);
        x = fmaxf(x, 0.f);
    }
    float2 s = block_sum2((tid < H2) ? x : 0.f, (tid < H2) ? x * x : 0.f, tid, red8);
    {
        float mu  = s.x * (1.f / H2);
        float var = s.y * (1.f / H2) - mu * mu;
        if (tid < H2)
            comb[tid] = (x - mu) * fast_rsqrt(fmaxf(var, 0.f) + LN_EPS) * g1[tid] + be1[tid];
    }
    __syncthreads();

    // ---- Phase 4: layer 2 (128x128), quad-col x k-segment GEMV ----
    {
        const int q = tid & 31, seg = tid >> 5;        // q: col-quad 0..31, seg: 0..7
        const float* w2base = W2 + (size_t)(seg * 16) * H2 + q * 4;
        float ax = 0.f, ay = 0.f, az = 0.f, aw = 0.f;
        #pragma unroll
        for (int k = 0; k < 16; ++k) {
            float a = comb[seg * 16 + k];
            float4 w = *reinterpret_cast<const float4*>(w2base + (size_t)k * H2);
            ax = fmaf(a, w.x, ax); ay = fmaf(a, w.y, ay);
            az = fmaf(a, w.z, az); aw = fmaf(a, w.w, aw);
        }
        float4* p4 = reinterpret_cast<float4*>(part);
        p4[tid] = make_float4(ax, ay, az, aw);
    }
    __syncthreads();
    float x2 = 0.f;
    if (tid < H2) {
        float ssum = 0.f;
        #pragma unroll
        for (int sg = 0; sg < 8; ++sg) ssum += part[sg * 128 + tid];
        x2 = fmaxf(ssum + b2[tid], 0.f);
    }
    s = block_sum2((tid < H2) ? x2 : 0.f, (tid < H2) ? x2 * x2 : 0.f, tid, red8);
    {
        float mu  = s.x * (1.f / H2);
        float var = s.y * (1.f / H2) - mu * mu;
        if (tid < H2)
            comb[H2 + tid] = (x2 - mu) * fast_rsqrt(fmaxf(var, 0.f) + LN_EPS) * g2[tid] + be2[tid];
    }
    __syncthreads();

    // write combined (all 256 values ready)
    out_combined[(size_t)b * HID + tid] = comb[tid];

    // ---- Phase 5: classifier 256->64, quad-col x k-segment GEMV ----
    {
        const int q = tid & 15, seg = tid >> 4;        // q: 0..15, seg: 0..15
        const float* wcbase = Wc1 + (size_t)(seg * 16) * 64 + q * 4;
        float ax = 0.f, ay = 0.f, az = 0.f, aw = 0.f;
        #pragma unroll
        for (int k = 0; k < 16; ++k) {
            float a = comb[seg * 16 + k];
            float4 w = *reinterpret_cast<const float4*>(wcbase + (size_t)k * 64);
            ax = fmaf(a, w.x, ax); ay = fmaf(a, w.y, ay);
            az = fmaf(a, w.z, az); aw = fmaf(a, w.w, aw);
        }
        float4* p4 = reinterpret_cast<float4*>(part);
        p4[tid] = make_float4(ax, ay, az, aw);
    }
    __syncthreads();

    // ---- Phase 6: 64->4 logits + softmax, single wave ----
    if (tid < 64) {
        float ssum = 0.f;
        #pragma unroll
        for (int sg = 0; sg < 16; ++sg) ssum += part[sg * 64 + tid];
        float c1 = fmaxf(ssum + bc1[tid], 0.f);

        float4 wrow = reinterpret_cast<const float4*>(Wc2)[tid];   // Wc2[j][0..3]
        float lx = c1 * wrow.x, ly = c1 * wrow.y, lz = c1 * wrow.z, lw = c1 * wrow.w;
        #pragma unroll
        for (int off = 32; off; off >>= 1) {
            lx += __shfl_down(lx, off);
            ly += __shfl_down(ly, off);
            lz += __shfl_down(lz, off);
            lw += __shfl_down(lw, off);
        }
        if (tid == 0) {
            float4 bb = *reinterpret_cast<const float4*>(bc2);
            float l0 = lx + bb.x, l1 = ly + bb.y, l2 = lz + bb.z, l3 = lw + bb.w;
            float m  = fmaxf(fmaxf(l0, l1), fmaxf(l2, l3));
            float e0 = __expf(l0 - m), e1 = __expf(l1 - m);
            float e2 = __expf(l2 - m), e3 = __expf(l3 - m);
            float inv = 1.f / (e0 + e1 + e2 + e3);
            reinterpret_cast<float4*>(out_regime)[b] =
                make_float4(e0 * inv, e1 * inv, e2 * inv, e3 * inv);
        }
    }
}

extern "C" void kernel_launch(void* const* d_in, const int* in_sizes, int n_in,
                              void* d_out, int out_size, void* d_ws, size_t ws_size,
                              hipStream_t stream) {
    const float* prices = (const float*)d_in[0];
    const float* W1  = (const float*)d_in[1];
    const float* b1  = (const float*)d_in[2];
    const float* g1  = (const float*)d_in[3];
    const float* be1 = (const float*)d_in[4];
    const float* W2  = (const float*)d_in[5];
    const float* b2  = (const float*)d_in[6];
    const float* g2  = (const float*)d_in[7];
    const float* be2 = (const float*)d_in[8];
    const float* Wc1 = (const float*)d_in[9];
    const float* bc1 = (const float*)d_in[10];
    const float* Wc2 = (const float*)d_in[11];
    const float* bc2 = (const float*)d_in[12];

    const int B = in_sizes[0] / S;
    float* out_combined = (float*)d_out;
    float* out_regime   = (float*)d_out + (size_t)B * HID;

    vol_fused<<<B, 256, 0, stream>>>(prices, W1, b1, g1, be1, W2, b2, g2, be2,
                                     Wc1, bc1, Wc2, bc2, out_combined, out_regime);
}